// Round 10
// baseline (82.052 us; speedup 1.0000x reference)
//
#include <hip/hip_runtime.h>
#include <hip/hip_bf16.h>

// Problem constants (from reference setup_inputs)
#define BDIM 256     // batch
#define NDIM 1152    // route nodes
#define CIN 8
#define KDIM 10      // num capsule groups
#define COUT 16
#define NTHREADS 512
#define BT 4         // batches per block -> W[k] read ONCE per 4 b's (755->377 MB L2)
#define NPT 9        // n values per thread = NDIM / 128

// Block = (k, b-quad), 512 threads, 1 block/CU (LDS 157.7 KB of 160 KB).
// Thread t owns co-quad coq=t&3 at n = (t>>2)+128j for ALL 4 batches.
// predS: bf16x2 in two halves (b0b1 | b2b3), uint4 per (n,coq) each ->
// ds_read/write_b128 at byte addr 16*lane (the proven conflict-free pattern).
// W loads: float4, 4 coq-lanes cover each 64B line exactly once.
// No max-subtraction in softmax (|p*vc| << 88). Squash via single division:
// s = sp/se, v = s|s|/(1+s^2) == sp*|sp|/(se^2+sp^2)  (se > 0 always).
//
// Spill discipline (R5-R9 lesson: spills come from load BATCHING):
//  - phase-1 j-loop unroll 1; W loads in pairs with sched_barrier(0) fences
//  - reduction-read loops unroll 1
//  - at 1 block/CU the allocator may use up to 256 VGPR anyway.

#if defined(__has_builtin)
#  if __has_builtin(__builtin_amdgcn_exp2f)
#    define EXP2F(x) __builtin_amdgcn_exp2f(x)
#  endif
#  if __has_builtin(__builtin_amdgcn_rcpf)
#    define RCPF(x) __builtin_amdgcn_rcpf(x)
#  endif
#endif
#ifndef EXP2F
#  define EXP2F(x) exp2f(x)
#endif
#ifndef RCPF
#  define RCPF(x) (1.0f / (x))
#endif
#define LOG2E 1.4426950408889634f

__device__ __forceinline__ unsigned pack2(float a, float b) {   // v_cvt_pk_bf16_f32
    union { __hip_bfloat162 h; unsigned u; } cv;
    cv.h = __float22bfloat162_rn(make_float2(a, b));
    return cv.u;
}
__device__ __forceinline__ float bf_lo(unsigned u) { return __uint_as_float(u << 16); }
__device__ __forceinline__ float bf_hi(unsigned u) { return __uint_as_float(u & 0xffff0000u); }

// 16 FMAs: one W float4 (one i) against all 4 batches' x scalar
#define FMA16(i, w4)                                                     \
    a0[0] = fmaf(xs0[i], (w4).x, a0[0]);                                 \
    a0[1] = fmaf(xs0[i], (w4).y, a0[1]);                                 \
    a0[2] = fmaf(xs0[i], (w4).z, a0[2]);                                 \
    a0[3] = fmaf(xs0[i], (w4).w, a0[3]);                                 \
    a1[0] = fmaf(xs1[i], (w4).x, a1[0]);                                 \
    a1[1] = fmaf(xs1[i], (w4).y, a1[1]);                                 \
    a1[2] = fmaf(xs1[i], (w4).z, a1[2]);                                 \
    a1[3] = fmaf(xs1[i], (w4).w, a1[3]);                                 \
    a2[0] = fmaf(xs2[i], (w4).x, a2[0]);                                 \
    a2[1] = fmaf(xs2[i], (w4).y, a2[1]);                                 \
    a2[2] = fmaf(xs2[i], (w4).z, a2[2]);                                 \
    a2[3] = fmaf(xs2[i], (w4).w, a2[3]);                                 \
    a3[0] = fmaf(xs3[i], (w4).x, a3[0]);                                 \
    a3[1] = fmaf(xs3[i], (w4).y, a3[1]);                                 \
    a3[2] = fmaf(xs3[i], (w4).z, a3[2]);                                 \
    a3[3] = fmaf(xs3[i], (w4).w, a3[3]);

__global__ __attribute__((amdgpu_flat_work_group_size(NTHREADS, NTHREADS),
                          amdgpu_waves_per_eu(2, 2)))
void capsule_routing_kernel(const float* __restrict__ x,      // [B, N, CIN]
                            const float* __restrict__ w,      // [K, N, CIN, COUT]
                            const int*   __restrict__ niter_p,
                            float*       __restrict__ out)    // [K, B, COUT]
{
    __shared__ uint4  predS[2][NDIM * 4];  // [half][n*4+coq]: b0b1 | b2b3, 147456 B
    __shared__ float4 redP[8][4][BT];      // [wv][coq][bb] psum, 2048 B
    __shared__ float4 redI[2][8][4][2*BT]; // [buf][wv][coq][se b0..3, sp b0..3], 8192 B

    const int blk = blockIdx.x;
    const int k   = blk >> 6;              // / (BDIM/BT) == 64
    const int b0  = (blk & 63) * BT;
    const int t   = threadIdx.x;
    const int wv  = t >> 6;
    const int l   = t & 63;
    const int coq = t & 3;                 // co = coq*4 .. coq*4+3
    const int nb  = t >> 2;                // base n (0..127)

    const float* __restrict__ xb0 = x + (size_t)b0 * NDIM * CIN;
    const float* __restrict__ xb1 = xb0 + NDIM * CIN;
    const float* __restrict__ xb2 = xb1 + NDIM * CIN;
    const float* __restrict__ xb3 = xb2 + NDIM * CIN;
    const float* __restrict__ wk  = w + (size_t)k * NDIM * CIN * COUT + coq * 4;

    float ps0[4] = {0.f,0.f,0.f,0.f}, ps1[4] = {0.f,0.f,0.f,0.f};
    float ps2[4] = {0.f,0.f,0.f,0.f}, ps3[4] = {0.f,0.f,0.f,0.f};

    // -------- Phase 1: pred for 4 batches + fused per-thread sum --------
#pragma unroll 1
    for (int j = 0; j < NPT; ++j) {
        const int n = nb + 128 * j;
        const float4 xa0 = *reinterpret_cast<const float4*>(xb0 + n * CIN);
        const float4 xc0 = *reinterpret_cast<const float4*>(xb0 + n * CIN + 4);
        const float4 xa1 = *reinterpret_cast<const float4*>(xb1 + n * CIN);
        const float4 xc1 = *reinterpret_cast<const float4*>(xb1 + n * CIN + 4);
        const float4 xa2 = *reinterpret_cast<const float4*>(xb2 + n * CIN);
        const float4 xc2 = *reinterpret_cast<const float4*>(xb2 + n * CIN + 4);
        const float4 xa3 = *reinterpret_cast<const float4*>(xb3 + n * CIN);
        const float4 xc3 = *reinterpret_cast<const float4*>(xb3 + n * CIN + 4);
        const float xs0[8] = {xa0.x,xa0.y,xa0.z,xa0.w,xc0.x,xc0.y,xc0.z,xc0.w};
        const float xs1[8] = {xa1.x,xa1.y,xa1.z,xa1.w,xc1.x,xc1.y,xc1.z,xc1.w};
        const float xs2[8] = {xa2.x,xa2.y,xa2.z,xa2.w,xc2.x,xc2.y,xc2.z,xc2.w};
        const float xs3[8] = {xa3.x,xa3.y,xa3.z,xa3.w,xc3.x,xc3.y,xc3.z,xc3.w};
        const float* wr = wk + (size_t)n * (CIN * COUT);
        float a0[4] = {0.f,0.f,0.f,0.f}, a1[4] = {0.f,0.f,0.f,0.f};
        float a2[4] = {0.f,0.f,0.f,0.f}, a3[4] = {0.f,0.f,0.f,0.f};
        {   // i = 0,1
            const float4 wA = *reinterpret_cast<const float4*>(wr);
            const float4 wB = *reinterpret_cast<const float4*>(wr + COUT);
            FMA16(0, wA); FMA16(1, wB);
        }
        __builtin_amdgcn_sched_barrier(0);  // bound W loads in flight to 2
        {   // i = 2,3
            const float4 wA = *reinterpret_cast<const float4*>(wr + 2 * COUT);
            const float4 wB = *reinterpret_cast<const float4*>(wr + 3 * COUT);
            FMA16(2, wA); FMA16(3, wB);
        }
        __builtin_amdgcn_sched_barrier(0);
        {   // i = 4,5
            const float4 wA = *reinterpret_cast<const float4*>(wr + 4 * COUT);
            const float4 wB = *reinterpret_cast<const float4*>(wr + 5 * COUT);
            FMA16(4, wA); FMA16(5, wB);
        }
        __builtin_amdgcn_sched_barrier(0);
        {   // i = 6,7
            const float4 wA = *reinterpret_cast<const float4*>(wr + 6 * COUT);
            const float4 wB = *reinterpret_cast<const float4*>(wr + 7 * COUT);
            FMA16(6, wA); FMA16(7, wB);
        }
        uint4 qA, qB;
        qA.x = pack2(a0[0], a0[1]);
        qA.y = pack2(a0[2], a0[3]);
        qA.z = pack2(a1[0], a1[1]);
        qA.w = pack2(a1[2], a1[3]);
        qB.x = pack2(a2[0], a2[1]);
        qB.y = pack2(a2[2], a2[3]);
        qB.z = pack2(a3[0], a3[1]);
        qB.w = pack2(a3[2], a3[3]);
        predS[0][n * 4 + coq] = qA;        // ds_write_b128, addr = 16*lane
        predS[1][n * 4 + coq] = qB;
#pragma unroll
        for (int c = 0; c < 4; ++c) {
            ps0[c] += a0[c]; ps1[c] += a1[c];
            ps2[c] += a2[c]; ps3[c] += a3[c];
        }
    }

    // intra-wave reduce over the 16 lanes sharing coq
#pragma unroll
    for (int m = 4; m < 64; m <<= 1) {
#pragma unroll
        for (int c = 0; c < 4; ++c) {
            ps0[c] += __shfl_xor(ps0[c], m, 64);
            ps1[c] += __shfl_xor(ps1[c], m, 64);
            ps2[c] += __shfl_xor(ps2[c], m, 64);
            ps3[c] += __shfl_xor(ps3[c], m, 64);
        }
    }
    if (l < 4) {                            // lane l holds coq == l
        redP[wv][l][0] = make_float4(ps0[0], ps0[1], ps0[2], ps0[3]);
        redP[wv][l][1] = make_float4(ps1[0], ps1[1], ps1[2], ps1[3]);
        redP[wv][l][2] = make_float4(ps2[0], ps2[1], ps2[2], ps2[3]);
        redP[wv][l][3] = make_float4(ps3[0], ps3[1], ps3[2], ps3[3]);
    }
    __syncthreads();
    float sT0[4] = {0.f,0.f,0.f,0.f}, sT1[4] = {0.f,0.f,0.f,0.f};
    float sT2[4] = {0.f,0.f,0.f,0.f}, sT3[4] = {0.f,0.f,0.f,0.f};
#pragma unroll 1
    for (int wvi = 0; wvi < 8; ++wvi) {
        const float4 r0 = redP[wvi][coq][0];
        const float4 r1 = redP[wvi][coq][1];
        const float4 r2 = redP[wvi][coq][2];
        const float4 r3 = redP[wvi][coq][3];
        sT0[0] += r0.x; sT0[1] += r0.y; sT0[2] += r0.z; sT0[3] += r0.w;
        sT1[0] += r1.x; sT1[1] += r1.y; sT1[2] += r1.z; sT1[3] += r1.w;
        sT2[0] += r2.x; sT2[1] += r2.y; sT2[2] += r2.z; sT2[3] += r2.w;
        sT3[0] += r3.x; sT3[1] += r3.y; sT3[2] += r3.z; sT3[3] += r3.w;
    }

    const int niter = *niter_p;

    // Iteration 1: logits == 0 -> uniform softmax -> s = mean_n(pred)
    // v = s|s|/(1+s^2) with s = sT/N  ==  sT*|sT| / (N^2 + sT^2)
    float v0[4], v1[4], v2[4], v3[4];
    float vc0[4], vc1[4], vc2[4], vc3[4];
    {
        const float N2 = (float)NDIM * (float)NDIM;
#pragma unroll
        for (int c = 0; c < 4; ++c) {
            v0[c] = sT0[c] * fabsf(sT0[c]) * RCPF(fmaf(sT0[c], sT0[c], N2));
            v1[c] = sT1[c] * fabsf(sT1[c]) * RCPF(fmaf(sT1[c], sT1[c], N2));
            v2[c] = sT2[c] * fabsf(sT2[c]) * RCPF(fmaf(sT2[c], sT2[c], N2));
            v3[c] = sT3[c] * fabsf(sT3[c]) * RCPF(fmaf(sT3[c], sT3[c], N2));
            vc0[c] = v0[c]; vc1[c] = v1[c]; vc2[c] = v2[c]; vc3[c] = v3[c];
        }
    }

    for (int it = 1; it < niter; ++it) {
        const int itb = it & 1;
        // fold log2(e) into vc once: exp(p*vc) == exp2(p * (vc*log2e))
        float vl0[4], vl1[4], vl2[4], vl3[4];
#pragma unroll
        for (int c = 0; c < 4; ++c) {
            vl0[c] = vc0[c] * LOG2E; vl1[c] = vc1[c] * LOG2E;
            vl2[c] = vc2[c] * LOG2E; vl3[c] = vc3[c] * LOG2E;
        }
        float se0[4]={0.f,0.f,0.f,0.f}, sp0[4]={0.f,0.f,0.f,0.f};
        float se1[4]={0.f,0.f,0.f,0.f}, sp1[4]={0.f,0.f,0.f,0.f};
        float se2[4]={0.f,0.f,0.f,0.f}, sp2[4]={0.f,0.f,0.f,0.f};
        float se3[4]={0.f,0.f,0.f,0.f}, sp3[4]={0.f,0.f,0.f,0.f};
#pragma unroll 1
        for (int j = 0; j < NPT; ++j) {
            const int n = nb + 128 * j;
            const uint4 qA = predS[0][n * 4 + coq];   // ds_read_b128
            const uint4 qB = predS[1][n * 4 + coq];
            const float p0[4] = {bf_lo(qA.x), bf_hi(qA.x), bf_lo(qA.y), bf_hi(qA.y)};
            const float p1[4] = {bf_lo(qA.z), bf_hi(qA.z), bf_lo(qA.w), bf_hi(qA.w)};
            const float p2[4] = {bf_lo(qB.x), bf_hi(qB.x), bf_lo(qB.y), bf_hi(qB.y)};
            const float p3[4] = {bf_lo(qB.z), bf_hi(qB.z), bf_lo(qB.w), bf_hi(qB.w)};
#pragma unroll
            for (int c = 0; c < 4; ++c) {
                const float e0 = EXP2F(p0[c] * vl0[c]);
                se0[c] += e0; sp0[c] = fmaf(e0, p0[c], sp0[c]);
                const float e1 = EXP2F(p1[c] * vl1[c]);
                se1[c] += e1; sp1[c] = fmaf(e1, p1[c], sp1[c]);
                const float e2 = EXP2F(p2[c] * vl2[c]);
                se2[c] += e2; sp2[c] = fmaf(e2, p2[c], sp2[c]);
                const float e3 = EXP2F(p3[c] * vl3[c]);
                se3[c] += e3; sp3[c] = fmaf(e3, p3[c], sp3[c]);
            }
        }
#pragma unroll
        for (int m = 4; m < 64; m <<= 1) {
#pragma unroll
            for (int c = 0; c < 4; ++c) {
                se0[c] += __shfl_xor(se0[c], m, 64);
                sp0[c] += __shfl_xor(sp0[c], m, 64);
                se1[c] += __shfl_xor(se1[c], m, 64);
                sp1[c] += __shfl_xor(sp1[c], m, 64);
                se2[c] += __shfl_xor(se2[c], m, 64);
                sp2[c] += __shfl_xor(sp2[c], m, 64);
                se3[c] += __shfl_xor(se3[c], m, 64);
                sp3[c] += __shfl_xor(sp3[c], m, 64);
            }
        }
        if (l < 4) {
            redI[itb][wv][l][0] = make_float4(se0[0], se0[1], se0[2], se0[3]);
            redI[itb][wv][l][1] = make_float4(se1[0], se1[1], se1[2], se1[3]);
            redI[itb][wv][l][2] = make_float4(se2[0], se2[1], se2[2], se2[3]);
            redI[itb][wv][l][3] = make_float4(se3[0], se3[1], se3[2], se3[3]);
            redI[itb][wv][l][4] = make_float4(sp0[0], sp0[1], sp0[2], sp0[3]);
            redI[itb][wv][l][5] = make_float4(sp1[0], sp1[1], sp1[2], sp1[3]);
            redI[itb][wv][l][6] = make_float4(sp2[0], sp2[1], sp2[2], sp2[3]);
            redI[itb][wv][l][7] = make_float4(sp3[0], sp3[1], sp3[2], sp3[3]);
        }
        __syncthreads();   // double-buffered redI: one barrier per iteration
        float seT0[4]={0.f,0.f,0.f,0.f}, spT0[4]={0.f,0.f,0.f,0.f};
        float seT1[4]={0.f,0.f,0.f,0.f}, spT1[4]={0.f,0.f,0.f,0.f};
        float seT2[4]={0.f,0.f,0.f,0.f}, spT2[4]={0.f,0.f,0.f,0.f};
        float seT3[4]={0.f,0.f,0.f,0.f}, spT3[4]={0.f,0.f,0.f,0.f};
#pragma unroll 1
        for (int wvi = 0; wvi < 8; ++wvi) {
            const float4 ra = redI[itb][wvi][coq][0];
            const float4 rb = redI[itb][wvi][coq][1];
            const float4 rc = redI[itb][wvi][coq][2];
            const float4 rd = redI[itb][wvi][coq][3];
            seT0[0]+=ra.x; seT0[1]+=ra.y; seT0[2]+=ra.z; seT0[3]+=ra.w;
            seT1[0]+=rb.x; seT1[1]+=rb.y; seT1[2]+=rb.z; seT1[3]+=rb.w;
            seT2[0]+=rc.x; seT2[1]+=rc.y; seT2[2]+=rc.z; seT2[3]+=rc.w;
            seT3[0]+=rd.x; seT3[1]+=rd.y; seT3[2]+=rd.z; seT3[3]+=rd.w;
            const float4 re = redI[itb][wvi][coq][4];
            const float4 rf = redI[itb][wvi][coq][5];
            const float4 rg = redI[itb][wvi][coq][6];
            const float4 rh = redI[itb][wvi][coq][7];
            spT0[0]+=re.x; spT0[1]+=re.y; spT0[2]+=re.z; spT0[3]+=re.w;
            spT1[0]+=rf.x; spT1[1]+=rf.y; spT1[2]+=rf.z; spT1[3]+=rf.w;
            spT2[0]+=rg.x; spT2[1]+=rg.y; spT2[2]+=rg.z; spT2[3]+=rg.w;
            spT3[0]+=rh.x; spT3[1]+=rh.y; spT3[2]+=rh.z; spT3[3]+=rh.w;
        }
        // v = sp*|sp| / (se^2 + sp^2); vc += v   (se > 0 always)
#pragma unroll
        for (int c = 0; c < 4; ++c) {
            v0[c] = spT0[c] * fabsf(spT0[c]) *
                    RCPF(fmaf(seT0[c], seT0[c], spT0[c] * spT0[c]));
            v1[c] = spT1[c] * fabsf(spT1[c]) *
                    RCPF(fmaf(seT1[c], seT1[c], spT1[c] * spT1[c]));
            v2[c] = spT2[c] * fabsf(spT2[c]) *
                    RCPF(fmaf(seT2[c], seT2[c], spT2[c] * spT2[c]));
            v3[c] = spT3[c] * fabsf(spT3[c]) *
                    RCPF(fmaf(seT3[c], seT3[c], spT3[c] * spT3[c]));
            vc0[c] += v0[c]; vc1[c] += v1[c];
            vc2[c] += v2[c]; vc3[c] += v3[c];
        }
    }

    if (t < 4) {   // coq == t
        float4 o;
        o = make_float4(v0[0], v0[1], v0[2], v0[3]);
        *reinterpret_cast<float4*>(out + ((size_t)k * BDIM + b0)     * COUT + t * 4) = o;
        o = make_float4(v1[0], v1[1], v1[2], v1[3]);
        *reinterpret_cast<float4*>(out + ((size_t)k * BDIM + b0 + 1) * COUT + t * 4) = o;
        o = make_float4(v2[0], v2[1], v2[2], v2[3]);
        *reinterpret_cast<float4*>(out + ((size_t)k * BDIM + b0 + 2) * COUT + t * 4) = o;
        o = make_float4(v3[0], v3[1], v3[2], v3[3]);
        *reinterpret_cast<float4*>(out + ((size_t)k * BDIM + b0 + 3) * COUT + t * 4) = o;
    }
}

extern "C" void kernel_launch(void* const* d_in, const int* in_sizes, int n_in,
                              void* d_out, int out_size, void* d_ws, size_t ws_size,
                              hipStream_t stream) {
    const float* x = (const float*)d_in[0];
    const float* w = (const float*)d_in[1];
    const int* niter = (const int*)d_in[2];
    float* out = (float*)d_out;

    const int grid = KDIM * (BDIM / BT);   // 640 blocks, k outer
    capsule_routing_kernel<<<grid, NTHREADS, 0, stream>>>(x, w, niter, out);
}